// Round 1
// baseline (579.808 us; speedup 1.0000x reference)
//
#include <hip/hip_runtime.h>

// ---------------- constants ----------------
#define B_SZ   512
#define K_SZ   512
#define N_CLS  100000
#define SCALE_ 64.0f
// margin: (0.8-0.45)/(110-10) = 0.0035
#define MSLOPE 0.0035f
#define L_A_   10.0f
#define U_A_   110.0f

typedef unsigned short u16;
typedef short bf16x8 __attribute__((ext_vector_type(8)));
typedef float f32x4 __attribute__((ext_vector_type(4)));
typedef u16   u16x8 __attribute__((ext_vector_type(8)));

static __device__ inline u16 f2bf(float f) {
    unsigned int u = __float_as_uint(f);
    unsigned int r = (u + 0x7FFFu + ((u >> 16) & 1u)) >> 16;  // RNE
    return (u16)r;
}

// ---------------- kernel A: per-row prep ----------------
// norms of x rows, x_unit -> bf16, cos_m/sin_m, g-term
__global__ __launch_bounds__(256) void prep_x(
    const float* __restrict__ x, u16* __restrict__ xu,
    float* __restrict__ cosm, float* __restrict__ sinm,
    float* __restrict__ gterm)
{
    int b = blockIdx.x;
    int tid = threadIdx.x;  // 256 threads, 2 elems each
    float v0 = x[b * K_SZ + tid];
    float v1 = x[b * K_SZ + 256 + tid];
    float s = v0 * v0 + v1 * v1;
    #pragma unroll
    for (int off = 32; off; off >>= 1) s += __shfl_down(s, off);
    __shared__ float red[4];
    if ((tid & 63) == 0) red[tid >> 6] = s;
    __syncthreads();
    float tot = red[0] + red[1] + red[2] + red[3];
    float norm = sqrtf(tot);
    float inv = 1.0f / norm;              // x_unit uses UNclamped norm
    xu[b * K_SZ + tid]       = f2bf(v0 * inv);
    xu[b * K_SZ + 256 + tid] = f2bf(v1 * inv);
    if (tid == 0) {
        float cl = fminf(fmaxf(norm, L_A_), U_A_);   // clamped norm
        float ada = MSLOPE * (cl - L_A_) + 0.45f;
        cosm[b] = cosf(ada);
        sinm[b] = sinf(ada);
        gterm[b] = cl * (1.0f / (U_A_ * U_A_)) + 1.0f / cl;
    }
}

// ---------------- kernel B: W column inv-norms ----------------
__global__ __launch_bounds__(256) void wnorm(
    const float* __restrict__ W, float* __restrict__ invw)
{
    int c = blockIdx.x * 256 + threadIdx.x;
    if (c >= N_CLS) return;
    float s = 0.f;
    #pragma unroll 8
    for (int k = 0; k < K_SZ; ++k) {
        float w = W[(size_t)k * N_CLS + c];
        s += w * w;
    }
    invw[c] = rsqrtf(s);
}

// ---------------- kernel C: GEMM + margin + partial sumexp ----------------
// tile: BM=128, BN=128, BK=64; 4 waves in 2x2; mfma 16x16x32 bf16
// LDS layout [k_oct][row/col][8] -> fragment reads are contiguous ds_read_b128
__global__ __launch_bounds__(256) void gemm_softmax(
    const u16* __restrict__ xu, const float* __restrict__ W,
    const float* __restrict__ invw, const float* __restrict__ cosm,
    const float* __restrict__ sinm, const int* __restrict__ target,
    float* __restrict__ rowsum, float* __restrict__ tgtl)
{
    __shared__ u16 As[8][128][8];   // 16 KB  (k_oct, row, 8k)
    __shared__ u16 Bs[8][128][8];   // 16 KB  (k_oct, col, 8k)

    int tid = threadIdx.x;
    int m0 = blockIdx.x * 128;
    int n0 = blockIdx.y * 128;
    int lane = tid & 63, wid = tid >> 6;
    int wr = (wid >> 1) * 64;   // wave row offset in tile
    int wc = (wid & 1) * 64;    // wave col offset in tile

    f32x4 acc[4][4] = {};

    for (int kt = 0; kt < K_SZ / 64; ++kt) {
        // stage A (bf16 x_unit, already k-contiguous): 4 x 16B per thread
        #pragma unroll
        for (int i = 0; i < 4; ++i) {
            int slot = i * 256 + tid;
            int ko = slot >> 7, row = slot & 127;
            const uint4* src = reinterpret_cast<const uint4*>(
                xu + (size_t)(m0 + row) * K_SZ + kt * 64 + ko * 8);
            *reinterpret_cast<uint4*>(&As[ko][row][0]) = *src;
        }
        // stage B: gather 8 k's of one column, convert fp32->bf16, one b128 write
        #pragma unroll
        for (int i = 0; i < 4; ++i) {
            int slot = i * 256 + tid;
            int ko = slot >> 7, col = slot & 127;
            int gc = n0 + col;
            u16x8 tmp;
            if (gc < N_CLS) {
                #pragma unroll
                for (int j = 0; j < 8; ++j) {
                    float w = W[(size_t)(kt * 64 + ko * 8 + j) * N_CLS + gc];
                    tmp[j] = f2bf(w);
                }
            } else {
                #pragma unroll
                for (int j = 0; j < 8; ++j) tmp[j] = 0;
            }
            *reinterpret_cast<u16x8*>(&Bs[ko][col][0]) = tmp;
        }
        __syncthreads();
        #pragma unroll
        for (int kk = 0; kk < 2; ++kk) {
            bf16x8 a[4], b[4];
            int ko = kk * 4 + (lane >> 4);
            int sel = lane & 15;
            #pragma unroll
            for (int m = 0; m < 4; ++m)
                a[m] = *reinterpret_cast<const bf16x8*>(&As[ko][wr + m * 16 + sel][0]);
            #pragma unroll
            for (int n = 0; n < 4; ++n)
                b[n] = *reinterpret_cast<const bf16x8*>(&Bs[ko][wc + n * 16 + sel][0]);
            #pragma unroll
            for (int m = 0; m < 4; ++m)
                #pragma unroll
                for (int n = 0; n < 4; ++n)
                    acc[m][n] = __builtin_amdgcn_mfma_f32_16x16x32_bf16(
                        a[m], b[n], acc[m][n], 0, 0, 0);
        }
        __syncthreads();
    }

    // epilogue: cos -> logits (+margin at target) -> exp(logit-64), per-row sums
    int cloc = lane & 15;   // C col within 16
    int rgrp = lane >> 4;   // C row group
    float iw[4]; int cols[4];
    #pragma unroll
    for (int n = 0; n < 4; ++n) {
        int c = n0 + wc + n * 16 + cloc;
        cols[n] = c;
        iw[n] = (c < N_CLS) ? invw[c] : 0.f;
    }
    #pragma unroll
    for (int m = 0; m < 4; ++m) {
        #pragma unroll
        for (int j = 0; j < 4; ++j) {
            int row = m0 + wr + m * 16 + rgrp * 4 + j;
            float cm = cosm[row], sm = sinm[row];
            int tg = target[row];
            float s = 0.f;
            #pragma unroll
            for (int n = 0; n < 4; ++n) {
                if (cols[n] < N_CLS) {
                    float cosv = acc[m][n][j] * iw[n];
                    cosv = fminf(fmaxf(cosv, -1.f), 1.f);
                    float logit = SCALE_ * cosv;
                    if (cols[n] == tg) {
                        float st = sqrtf(fmaxf(0.f, 1.f - cosv * cosv));
                        float cmm = (cosv > 0.f) ? (cosv * cm - st * sm) : cosv;
                        logit = SCALE_ * cmm;
                        tgtl[row] = logit;   // unique writer
                    }
                    s += __expf(logit - SCALE_);
                }
            }
            // reduce across the 16 lanes sharing this row (bits 0..3 of lane)
            #pragma unroll
            for (int off = 1; off < 16; off <<= 1) s += __shfl_xor(s, off);
            if (cloc == 0) atomicAdd(&rowsum[row], s);
        }
    }
}

// ---------------- kernel D: finalize ----------------
__global__ __launch_bounds__(512) void finalize(
    const float* __restrict__ rowsum, const float* __restrict__ tgtl,
    const float* __restrict__ gterm, float* __restrict__ out)
{
    int tid = threadIdx.x;
    float v = 0.f;
    if (tid < B_SZ) {
        float ce = SCALE_ + logf(rowsum[tid]) - tgtl[tid];
        v = ce + 20.f * gterm[tid];
    }
    #pragma unroll
    for (int off = 32; off; off >>= 1) v += __shfl_down(v, off);
    __shared__ float red[8];
    if ((tid & 63) == 0) red[tid >> 6] = v;
    __syncthreads();
    if (tid == 0) {
        float t = 0.f;
        #pragma unroll
        for (int i = 0; i < 8; ++i) t += red[i];
        out[0] = t / (float)B_SZ;
    }
}

// ---------------- launch ----------------
extern "C" void kernel_launch(void* const* d_in, const int* in_sizes, int n_in,
                              void* d_out, int out_size, void* d_ws, size_t ws_size,
                              hipStream_t stream)
{
    const float* x      = (const float*)d_in[0];
    const int*   target = (const int*)d_in[1];
    const float* W      = (const float*)d_in[2];
    float* out = (float*)d_out;

    char* ws = (char*)d_ws;
    u16*   xu     = (u16*)(ws);                    // 512*512*2 = 524288
    float* cosm   = (float*)(ws + 524288);         // 2048
    float* sinm   = (float*)(ws + 526336);         // 2048
    float* gterm  = (float*)(ws + 528384);         // 2048
    float* tgtl   = (float*)(ws + 530432);         // 2048
    float* rowsum = (float*)(ws + 532480);         // 2048
    float* invw   = (float*)(ws + 534528);         // 400000

    hipMemsetAsync(rowsum, 0, B_SZ * sizeof(float), stream);

    prep_x<<<B_SZ, 256, 0, stream>>>(x, xu, cosm, sinm, gterm);
    wnorm<<<(N_CLS + 255) / 256, 256, 0, stream>>>(W, invw);
    dim3 grid(B_SZ / 128, (N_CLS + 127) / 128);
    gemm_softmax<<<grid, 256, 0, stream>>>(xu, W, invw, cosm, sinm, target,
                                           rowsum, tgtl);
    finalize<<<1, 512, 0, stream>>>(rowsum, tgtl, gterm, out);
}